// Round 2
// baseline (15963.364 us; speedup 1.0000x reference)
//
#include <hip/hip_runtime.h>

#define S_LEN 2048

typedef _Float16 f16;
typedef _Float16 f16x8 __attribute__((ext_vector_type(8)));
typedef float f32x4 __attribute__((ext_vector_type(4)));

__device__ __forceinline__ float sigf(float x) {
  x = fminf(fmaxf(x, -30.f), 30.f);
  float e = __builtin_amdgcn_exp2f(-1.44269504089f * x);
  return __builtin_amdgcn_rcpf(1.f + e);
}
__device__ __forceinline__ float tanh_fast(float x) {
  x = fminf(fmaxf(x, -15.f), 15.f);
  float e = __builtin_amdgcn_exp2f(2.88539008178f * x);  // e^(2x)
  return 1.f - 2.f * __builtin_amdgcn_rcpf(e + 1.f);
}

__device__ __forceinline__ void st_flag(unsigned* p, unsigned v) {
  __hip_atomic_store(p, v, __ATOMIC_RELEASE, __HIP_MEMORY_SCOPE_AGENT);
}
__device__ __forceinline__ unsigned ld_flag(const unsigned* p) {
  return __hip_atomic_load(p, __ATOMIC_ACQUIRE, __HIP_MEMORY_SCOPE_AGENT);
}
__device__ __forceinline__ void st_hx(unsigned* p, unsigned v) {
  __hip_atomic_store(p, v, __ATOMIC_RELAXED, __HIP_MEMORY_SCOPE_AGENT);
}
__device__ __forceinline__ unsigned ld_hx(const unsigned* p) {
  return __hip_atomic_load(p, __ATOMIC_RELAXED, __HIP_MEMORY_SCOPE_AGENT);
}

// Build combined W16[1024][512] = [Whh | Wih] in f16, bias = bih + bhh, zero flags.
__global__ void convert_k(const float* __restrict__ Wih, const float* __restrict__ Whh,
                          const float* __restrict__ bih, const float* __restrict__ bhh,
                          f16* __restrict__ W16, float* __restrict__ bias,
                          unsigned* __restrict__ flags) {
  int i = blockIdx.x * blockDim.x + threadIdx.x;  // 524288 threads
  int n = i >> 9, k = i & 511;
  W16[i] = (f16)((k < 256) ? Whh[n * 256 + k] : Wih[n * 256 + (k - 256)]);
  if (i < 1024) bias[i] = bih[i] + bhh[i];
  if (i < 2048) flags[i] = 0u;
}

// Persistent LSTM: 64 wgs = 8 groups (8 batch rows) x 8 N-slices (32 h-dims each).
// W-slice resident in VGPRs (barr0/barr1 = 128 VGPRs/lane). Per step:
// gates = [h|x] @ Wslice^T via 32 MFMAs, fused update, h-slice all-gather via
// agent-scope atomics + monotonic flags. blockIdx = slice*8 + g so all slices
// of a group share an XCD (perf heuristic only).
__global__ __launch_bounds__(256, 1) void lstm_k(
    const f16* __restrict__ W16, const float* __restrict__ bias,
    const int* __restrict__ text, const float* __restrict__ embed,
    const float* __restrict__ mask, float* __restrict__ out,
    unsigned* __restrict__ hx, unsigned* __restrict__ flags) {
  __shared__ __align__(16) f16 h_sw[16 * 256];      // 8 KB, rows 0..7 real
  __shared__ __align__(16) f16 x_sw[4 * 16 * 256];  // 32 KB ring, rows 0..7 real
  __shared__ float gates[8 * 128];                  // 4 KB

  const int tid = threadIdx.x;
  const int g = blockIdx.x & 7;
  const int slice = blockIdx.x >> 3;
  const int b0 = g * 8;
  const int j0 = slice * 32;

  // MFMA lane mapping
  const int wv = tid >> 6;   // wave = gate index
  const int l = tid & 63;
  const int kg = l >> 4;
  const int c16 = l & 15;    // A row / D col
  const int asw = (c16 & 7) << 3;

  // update / gather / prefetch mapping: (r, jl)
  const int r = tid >> 5;    // 0..7 batch row
  const int jl = tid & 31;   // 0..31 dim within slice
  const int rsw = (r & 7) << 3;
  const int pd = jl * 8;     // x-prefetch dim base

  // zero h_sw (h0 = 0; padding rows may be anything, only D rows 0..7 are read)
  {
    f16x8 z = {(f16)0.f, (f16)0.f, (f16)0.f, (f16)0.f,
               (f16)0.f, (f16)0.f, (f16)0.f, (f16)0.f};
    *(f16x8*)&h_sw[tid * 16] = z;
    *(f16x8*)&h_sw[tid * 16 + 8] = z;
  }

  const float bi = bias[0 * 256 + j0 + jl];
  const float bf = bias[1 * 256 + j0 + jl];
  const float bg = bias[2 * 256 + j0 + jl];
  const float bo = bias[3 * 256 + j0 + jl];
  float cc = 0.f;

  // resident B fragments: rows n_global = wv*256 + j0 + ntl*16 + c16, k = kc*32+kg*8
  f16x8 barr0[16], barr1[16];
  {
    const f16* w0 = W16 + (size_t)(wv * 256 + j0 + 0 * 16 + c16) * 512 + kg * 8;
    const f16* w1 = W16 + (size_t)(wv * 256 + j0 + 1 * 16 + c16) * 512 + kg * 8;
#pragma unroll
    for (int kc = 0; kc < 16; kc++) {
      barr0[kc] = *(const f16x8*)(w0 + kc * 32);
      barr1[kc] = *(const f16x8*)(w1 + kc * 32);
    }
  }

  // x ring prologue: fill slots 0..3 (t = 0..3)
  const size_t trow = (size_t)(b0 + r) * S_LEN;
#pragma unroll 1
  for (int pf = 0; pf < 4; pf++) {
    int idx = text[trow + pf];
    const float4* ep = (const float4*)(embed + (size_t)idx * 256 + pd);
    float4 v0 = ep[0], v1 = ep[1];
    f16x8 hv = {(f16)v0.x, (f16)v0.y, (f16)v0.z, (f16)v0.w,
                (f16)v1.x, (f16)v1.y, (f16)v1.z, (f16)v1.w};
    *(f16x8*)&x_sw[pf * 4096 + ((r * 256 + pd) ^ rsw)] = hv;
  }
  // pipeline regs: rx holds x[t=4], idx_r holds text[t=5]
  float4 rxa, rxb;
  int idx_r;
  {
    int idx4 = text[trow + 4];
    const float4* ep = (const float4*)(embed + (size_t)idx4 * 256 + pd);
    rxa = ep[0];
    rxb = ep[1];
    idx_r = text[trow + 5];
  }
  __syncthreads();

  unsigned* flag_self = flags + (size_t)(g * 8 + slice) * 32;
  const unsigned* flag_base = flags + (size_t)(g * 8) * 32;

  for (int t = 0; t < S_LEN; t++) {
    float mv = mask[trow + t];

    // Phase 1: gates MFMA, A = [h | x_t], K = 512
    f32x4 acc0 = {0.f, 0.f, 0.f, 0.f}, acc1 = {0.f, 0.f, 0.f, 0.f};
    const f16* xs = x_sw + (t & 3) * 4096;
#pragma unroll
    for (int kc = 0; kc < 16; kc++) {
      const f16* ab = (kc < 8) ? h_sw : xs;
      f16x8 a = *(const f16x8*)(ab + ((c16 * 256 + (kc & 7) * 32 + kg * 8) ^ asw));
      acc0 = __builtin_amdgcn_mfma_f32_16x16x32_f16(a, barr0[kc], acc0, 0, 0, 0);
      acc1 = __builtin_amdgcn_mfma_f32_16x16x32_f16(a, barr1[kc], acc1, 0, 0, 0);
    }
    // Phase 2: D rows 0..7 (kg<2) -> gates LDS  [row][gate*32+jl]
    if (kg < 2) {
#pragma unroll
      for (int i = 0; i < 4; i++) {
        gates[(kg * 4 + i) * 128 + wv * 32 + c16] = acc0[i];
        gates[(kg * 4 + i) * 128 + wv * 32 + 16 + c16] = acc1[i];
      }
    }
    __syncthreads();  // A

    // Phase 3: fused update (one (r, jl) item per thread)
    float gi = gates[r * 128 + 0 + jl] + bi;
    float gf = gates[r * 128 + 32 + jl] + bf;
    float gG = gates[r * 128 + 64 + jl] + bg;
    float go = gates[r * 128 + 96 + jl] + bo;
    cc = sigf(gf) * cc + sigf(gi) * tanh_fast(gG);
    float h = sigf(go) * tanh_fast(cc);

    // Phase 4: publish h-slice (double-buffered by step parity)
    const int par = (t + 1) & 1;
    unsigned short hbits = __builtin_bit_cast(unsigned short, (f16)h);
    st_hx(hx + (((size_t)par * 8 + g) * 8 + slice) * 256 + r * 32 + jl, (unsigned)hbits);
    __threadfence();
    __syncthreads();  // B
    if (tid == 0) st_flag(flag_self, (unsigned)(t + 1));

    // Phase 5: slack work under partner latency
    out[(trow + t) * 256 + j0 + jl] = h * mv;
    h_sw[(r * 256 + j0 + jl) ^ rsw] = (f16)h;
    if (t + 4 < S_LEN) {  // write x[t+4] into slot (t+4)&3 == t&3 (already consumed)
      f16x8 hv = {(f16)rxa.x, (f16)rxa.y, (f16)rxa.z, (f16)rxa.w,
                  (f16)rxb.x, (f16)rxb.y, (f16)rxb.z, (f16)rxb.w};
      *(f16x8*)&x_sw[(t & 3) * 4096 + ((r * 256 + pd) ^ rsw)] = hv;
    }
    if (t + 5 < S_LEN) {  // issue loads for x[t+5]
      const float4* ep = (const float4*)(embed + (size_t)idx_r * 256 + pd);
      rxa = ep[0];
      rxb = ep[1];
    }
    if (t + 6 < S_LEN) idx_r = text[trow + t + 6];

    if (tid < 8 && tid != slice) {
      const unsigned* fp = flag_base + tid * 32;
      while (ld_flag(fp) < (unsigned)(t + 1)) __builtin_amdgcn_s_sleep(1);
    }
    __syncthreads();  // C

    // Phase 6: gather partner h-slices -> h_sw
#pragma unroll
    for (int p = 0; p < 8; p++) {
      if (p != slice) {
        unsigned v = ld_hx(hx + (((size_t)par * 8 + g) * 8 + p) * 256 + r * 32 + jl);
        h_sw[(r * 256 + p * 32 + jl) ^ rsw] = __builtin_bit_cast(f16, (unsigned short)(v & 0xffffu));
      }
    }
    __syncthreads();  // D
  }
}

extern "C" void kernel_launch(void* const* d_in, const int* in_sizes, int n_in,
                              void* d_out, int out_size, void* d_ws, size_t ws_size,
                              hipStream_t stream) {
  const int* text = (const int*)d_in[0];
  const float* mask = (const float*)d_in[1];
  // d_in[2] = len_seq: sort + inverse-sort is a no-op -> unused
  const float* embed = (const float*)d_in[3];
  const float* Wih = (const float*)d_in[4];
  const float* Whh = (const float*)d_in[5];
  const float* bih = (const float*)d_in[6];
  const float* bhh = (const float*)d_in[7];
  float* out = (float*)d_out;

  char* ws = (char*)d_ws;
  f16* W16 = (f16*)ws;                          // 1,048,576 B
  float* bias = (float*)(ws + 1048576);         // 4,096 B
  unsigned* flags = (unsigned*)(ws + 1052672);  // 8,192 B
  unsigned* hx = (unsigned*)(ws + 1060864);     // 131,072 B

  convert_k<<<2048, 256, 0, stream>>>(Wih, Whh, bih, bhh, W16, bias, flags);
  lstm_k<<<64, 256, 0, stream>>>(W16, bias, text, embed, mask, out, hx, flags);
}

// Round 3
// 2980.112 us; speedup vs baseline: 5.3566x; 5.3566x over previous
//
#include <hip/hip_runtime.h>

#define S_LEN 2048

typedef _Float16 f16;
typedef _Float16 f16x8 __attribute__((ext_vector_type(8)));
typedef float f32x4 __attribute__((ext_vector_type(4)));

__device__ __forceinline__ float sigf(float x) {
  x = fminf(fmaxf(x, -30.f), 30.f);
  float e = __builtin_amdgcn_exp2f(-1.44269504089f * x);
  return __builtin_amdgcn_rcpf(1.f + e);
}
__device__ __forceinline__ float tanh_fast(float x) {
  x = fminf(fmaxf(x, -15.f), 15.f);
  float e = __builtin_amdgcn_exp2f(2.88539008178f * x);  // e^(2x)
  return 1.f - 2.f * __builtin_amdgcn_rcpf(e + 1.f);
}

__device__ __forceinline__ void st_hx(unsigned* p, unsigned v) {
  __hip_atomic_store(p, v, __ATOMIC_RELAXED, __HIP_MEMORY_SCOPE_AGENT);
}
__device__ __forceinline__ unsigned ld_hx(const unsigned* p) {
  return __hip_atomic_load(p, __ATOMIC_RELAXED, __HIP_MEMORY_SCOPE_AGENT);
}
__device__ __forceinline__ float swz8(float v) {
  int i = __builtin_bit_cast(int, v);
  int r = __builtin_amdgcn_ds_swizzle(i, 0x201F);  // lane ^= 8
  return __builtin_bit_cast(float, r);
}

// Build W16[1024][512] = [Whh | Wih] f16, bias = bih + bhh, zero hx tag buffers.
__global__ void convert_k(const float* __restrict__ Wih, const float* __restrict__ Whh,
                          const float* __restrict__ bih, const float* __restrict__ bhh,
                          f16* __restrict__ W16, float* __restrict__ bias,
                          unsigned* __restrict__ hx) {
  int i = blockIdx.x * blockDim.x + threadIdx.x;  // 524288 threads
  int n = i >> 9, k = i & 511;
  W16[i] = (f16)((k < 256) ? Whh[n * 256 + k] : Wih[n * 256 + (k - 256)]);
  if (i < 1024) bias[i] = bih[i] + bhh[i];
  if (i < 32768) hx[i] = 0u;  // replay safety: stale tags would alias
}

// Persistent LSTM: 64 wgs = 8 groups (8 batch rows) x 8 N-slices (32 dims each).
// Waves partition by j-subrange (8 dims), each wave computes all 4 gates for its
// dims via two B tiles. Exchange = packed (tag|f16) relaxed-atomic words, no
// fences/flags; x-part MFMA for t+1 hides the exchange RTT. One barrier/step.
__global__ __launch_bounds__(256, 1) void lstm_k(
    const f16* __restrict__ W16, const float* __restrict__ bias,
    const int* __restrict__ text, const float* __restrict__ embed,
    const float* __restrict__ mask, float* __restrict__ out,
    unsigned* __restrict__ hx) {
  __shared__ __align__(16) f16 h_sw[2][16 * 256];  // 16 KB, parity buffers
  __shared__ __align__(16) f16 x_sw[4][16 * 256];  // 32 KB ring

  const int tid = threadIdx.x;
  const int g = blockIdx.x & 7;       // batch group (8 rows)
  const int slice = blockIdx.x >> 3;  // 32-dim N slice
  const int b0 = g * 8;
  const int j0 = slice * 32;

  // MFMA lane mapping: wave wv owns dims j0 + wv*8 .. +7
  const int wv = tid >> 6;
  const int l = tid & 63;
  const int kg = l >> 4;          // 0..3 (k-group; also D batch quartet)
  const int c16 = l & 15;         // B tile row / D col
  const int asw = (c16 & 7) << 3;
  const int gsel = c16 >> 3;      // 0: lane holds gates {i,g}; 1: {f,o}
  const int jloc = wv * 8 + (c16 & 7);
  const int jg = j0 + jloc;

  // prefetch / gather mapping
  const int r = tid >> 5;   // 0..7 batch row
  const int jl = tid & 31;  // dim-in-slice
  const int rsw = (r & 7) << 3;
  const int pd = jl * 8;

  // zero both h parity buffers (rows 8..15 = M padding, stay zero)
  {
    f16x8 z = {(f16)0.f, (f16)0.f, (f16)0.f, (f16)0.f,
               (f16)0.f, (f16)0.f, (f16)0.f, (f16)0.f};
    *(f16x8*)&h_sw[0][tid * 16] = z;
    *(f16x8*)&h_sw[0][tid * 16 + 8] = z;
    *(f16x8*)&h_sw[1][tid * 16] = z;
    *(f16x8*)&h_sw[1][tid * 16 + 8] = z;
  }

  const float bi = bias[0 * 256 + jg];
  const float bf = bias[1 * 256 + jg];
  const float bg = bias[2 * 256 + jg];
  const float bo = bias[3 * 256 + jg];

  // resident weights: tile0 rows = gate gsel, tile1 rows = gate 2+gsel, dim jg
  f16x8 barr0[16], barr1[16];
  {
    const f16* w0 = W16 + (size_t)(gsel * 256 + jg) * 512 + kg * 8;
    const f16* w1 = W16 + (size_t)((2 + gsel) * 256 + jg) * 512 + kg * 8;
#pragma unroll
    for (int kc = 0; kc < 16; kc++) {
      barr0[kc] = *(const f16x8*)(w0 + kc * 32);
      barr1[kc] = *(const f16x8*)(w1 + kc * 32);
    }
  }

  // update-lane batch assignment (lanes kg<2 do the update for 2 batches)
  const int upd = (kg < 2);
  const int bA = kg * 4 + gsel * 2;  // valid when upd
  const int bB = bA + 1;
  const int bAc = upd ? bA : 0;
  const int bBc = upd ? bB : 0;
  float ccA = 0.f, ccB = 0.f;

  // x ring prologue: slots 0..3 = x[0..3]
  const size_t trow = (size_t)(b0 + r) * S_LEN;
#pragma unroll 1
  for (int pf = 0; pf < 4; pf++) {
    int idx = text[trow + pf];
    const float4* ep = (const float4*)(embed + (size_t)idx * 256 + pd);
    float4 v0 = ep[0], v1 = ep[1];
    f16x8 hv = {(f16)v0.x, (f16)v0.y, (f16)v0.z, (f16)v0.w,
                (f16)v1.x, (f16)v1.y, (f16)v1.z, (f16)v1.w};
    *(f16x8*)&x_sw[pf][(r * 256 + pd) ^ rsw] = hv;
  }
  float4 rxa, rxb;
  int idx_r;
  {
    int idx4 = text[trow + 4];
    const float4* ep = (const float4*)(embed + (size_t)idx4 * 256 + pd);
    rxa = ep[0];
    rxb = ep[1];
    idx_r = text[trow + 5];
  }

  // partner hx offsets
  int offs[7];
#pragma unroll
  for (int p = 0; p < 7; p++) {
    int ps = p + (p >= slice);
    offs[p] = (g * 8 + ps) * 256 + r * 32 + jl;
  }
  const int own_off = (g * 8 + slice) * 256 + bAc * 32 + jloc;

  float mA = mask[(size_t)(b0 + bAc) * S_LEN];
  float mB = mask[(size_t)(b0 + bBc) * S_LEN];

  __syncthreads();

  // x-part accumulators for t=0
  f32x4 xacc0 = {0.f, 0.f, 0.f, 0.f}, xacc1 = {0.f, 0.f, 0.f, 0.f};
#pragma unroll
  for (int kc = 0; kc < 8; kc++) {
    f16x8 a = *(const f16x8*)&x_sw[0][(c16 * 256 + kc * 32 + kg * 8) ^ asw];
    xacc0 = __builtin_amdgcn_mfma_f32_16x16x32_f16(a, barr0[8 + kc], xacc0, 0, 0, 0);
    xacc1 = __builtin_amdgcn_mfma_f32_16x16x32_f16(a, barr1[8 + kc], xacc1, 0, 0, 0);
  }

  for (int t = 0; t < S_LEN; t++) {
    // h-part MFMA (critical): acc = xacc + h_t @ Whh-slice^T
    const f16* hs = h_sw[t & 1];
    f32x4 acc0 = xacc0, acc1 = xacc1;
#pragma unroll
    for (int kc = 0; kc < 8; kc++) {
      f16x8 a = *(const f16x8*)&hs[(c16 * 256 + kc * 32 + kg * 8) ^ asw];
      acc0 = __builtin_amdgcn_mfma_f32_16x16x32_f16(a, barr0[kc], acc0, 0, 0, 0);
      acc1 = __builtin_amdgcn_mfma_f32_16x16x32_f16(a, barr1[kc], acc1, 0, 0, 0);
    }

    // in-wave gate exchange: lane d <-> lane d^8 swaps the other two gates
    float o0_0 = swz8(acc0[0]), o0_1 = swz8(acc0[1]), o0_2 = swz8(acc0[2]), o0_3 = swz8(acc0[3]);
    float o1_0 = swz8(acc1[0]), o1_1 = swz8(acc1[1]), o1_2 = swz8(acc1[2]), o1_3 = swz8(acc1[3]);

    // batch A (i = gsel*2), batch B (i = gsel*2+1), all-constant vector indices
    float a0A = gsel ? acc0[2] : acc0[0], a1A = gsel ? acc1[2] : acc1[0];
    float x0A = gsel ? o0_2 : o0_0, x1A = gsel ? o1_2 : o1_0;
    float a0B = gsel ? acc0[3] : acc0[1], a1B = gsel ? acc1[3] : acc1[1];
    float x0B = gsel ? o0_3 : o0_1, x1B = gsel ? o1_3 : o1_1;

    float giA = (gsel ? x0A : a0A) + bi, gfA = (gsel ? a0A : x0A) + bf;
    float ggA = (gsel ? x1A : a1A) + bg, goA = (gsel ? a1A : x1A) + bo;
    float giB = (gsel ? x0B : a0B) + bi, gfB = (gsel ? a0B : x0B) + bf;
    float ggB = (gsel ? x1B : a1B) + bg, goB = (gsel ? a1B : x1B) + bo;

    ccA = sigf(gfA) * ccA + sigf(giA) * tanh_fast(ggA);
    float hA = sigf(goA) * tanh_fast(ccA);
    ccB = sigf(gfB) * ccB + sigf(giB) * tanh_fast(ggB);
    float hB = sigf(goB) * tanh_fast(ccB);

    const int par = (t + 1) & 1;
    unsigned* hb = hx + par * 16384;
    f16* hd = h_sw[par];

    // publish ASAP (relaxed, tag-in-word), then the deferred work
    if (upd) {
      unsigned wA = ((unsigned)(t + 1) << 16) |
                    (unsigned)__builtin_bit_cast(unsigned short, (f16)hA);
      unsigned wB = ((unsigned)(t + 1) << 16) |
                    (unsigned)__builtin_bit_cast(unsigned short, (f16)hB);
      st_hx(hb + own_off, wA);
      st_hx(hb + own_off + 32, wB);
      out[((size_t)(b0 + bA) * S_LEN + t) * 256 + jg] = hA * mA;
      out[((size_t)(b0 + bB) * S_LEN + t) * 256 + jg] = hB * mB;
      hd[(bA * 256 + jg) ^ ((bA & 7) << 3)] = (f16)hA;
      hd[(bB * 256 + jg) ^ ((bB & 7) << 3)] = (f16)hB;
    }

    if (t + 1 < S_LEN) {
      // mask prefetch for t+1
      mA = mask[(size_t)(b0 + bAc) * S_LEN + (t + 1)];
      mB = mask[(size_t)(b0 + bBc) * S_LEN + (t + 1)];

      // x-part MFMA for t+1 (independent of exchange -> hides RTT)
      const f16* xs = x_sw[(t + 1) & 3];
      f32x4 nx0 = {0.f, 0.f, 0.f, 0.f}, nx1 = {0.f, 0.f, 0.f, 0.f};
#pragma unroll
      for (int kc = 0; kc < 8; kc++) {
        f16x8 a = *(const f16x8*)&xs[(c16 * 256 + kc * 32 + kg * 8) ^ asw];
        nx0 = __builtin_amdgcn_mfma_f32_16x16x32_f16(a, barr0[8 + kc], nx0, 0, 0, 0);
        nx1 = __builtin_amdgcn_mfma_f32_16x16x32_f16(a, barr1[8 + kc], nx1, 0, 0, 0);
      }
      xacc0 = nx0;
      xacc1 = nx1;

      // x ring maintenance
      if (t + 4 < S_LEN) {
        f16x8 hv = {(f16)rxa.x, (f16)rxa.y, (f16)rxa.z, (f16)rxa.w,
                    (f16)rxb.x, (f16)rxb.y, (f16)rxb.z, (f16)rxb.w};
        *(f16x8*)&x_sw[t & 3][(r * 256 + pd) ^ rsw] = hv;
      }
      if (t + 5 < S_LEN) {
        const float4* ep = (const float4*)(embed + (size_t)idx_r * 256 + pd);
        rxa = ep[0];
        rxb = ep[1];
      }
      if (t + 6 < S_LEN) idx_r = text[trow + t + 6];

      // poll + gather partner h (masked parallel relaxed loads)
      const unsigned expv = (unsigned)(t + 1);
      unsigned need = 0x7fu;
      unsigned vals[7];
      do {
#pragma unroll
        for (int p = 0; p < 7; p++)
          if (need & (1u << p)) vals[p] = ld_hx(hb + offs[p]);
#pragma unroll
        for (int p = 0; p < 7; p++)
          if ((need & (1u << p)) && (vals[p] >> 16) == expv) need &= ~(1u << p);
      } while (need);
#pragma unroll
      for (int p = 0; p < 7; p++) {
        int ps = p + (p >= slice);
        hd[(r * 256 + ps * 32 + jl) ^ rsw] =
            __builtin_bit_cast(f16, (unsigned short)(vals[p] & 0xffffu));
      }
    }
    __syncthreads();
  }
}

extern "C" void kernel_launch(void* const* d_in, const int* in_sizes, int n_in,
                              void* d_out, int out_size, void* d_ws, size_t ws_size,
                              hipStream_t stream) {
  const int* text = (const int*)d_in[0];
  const float* mask = (const float*)d_in[1];
  // d_in[2] = len_seq: sort + inverse-sort is a no-op -> unused
  const float* embed = (const float*)d_in[3];
  const float* Wih = (const float*)d_in[4];
  const float* Whh = (const float*)d_in[5];
  const float* bih = (const float*)d_in[6];
  const float* bhh = (const float*)d_in[7];
  float* out = (float*)d_out;

  char* ws = (char*)d_ws;
  f16* W16 = (f16*)ws;                      // 1,048,576 B
  float* bias = (float*)(ws + 1048576);     // 4,096 B
  unsigned* hx = (unsigned*)(ws + 1052672); // 131,072 B (2 x 64 x 256 u32)

  convert_k<<<2048, 256, 0, stream>>>(Wih, Whh, bih, bhh, W16, bias, hx);
  lstm_k<<<64, 256, 0, stream>>>(W16, bias, text, embed, mask, out, hx);
}